// Round 11
// baseline (193.595 us; speedup 1.0000x reference)
//
#include <hip/hip_runtime.h>
#include <math.h>

#define IN_DIM 256
#define H_DIM  128
#define C_DIM  16
#define BK_SHIFT 8
#define BK_CAP   6144
#define CHUNK    4096

typedef __attribute__((ext_vector_type(8))) short bf16x8;
typedef __attribute__((ext_vector_type(4))) float f32x4;

__device__ __forceinline__ ushort f2bf(float f) {
    uint u = __float_as_uint(f);
    u += 0x7fffu + ((u >> 16) & 1u);   // round to nearest even
    return (ushort)(u >> 16);
}
__device__ __forceinline__ float bflo(uint v) { return __uint_as_float(v << 16); }
__device__ __forceinline__ float bfhi(uint v) { return __uint_as_float(v & 0xffff0000u); }
__device__ __forceinline__ uint pk2(float a, float b) {
    return (uint)f2bf(a) | ((uint)f2bf(b) << 16);
}

// ---------------- fused: zero bcnt + W1 cast/transpose + offsets[N]=E ----------------
__global__ __launch_bounds__(256) void k_prep(int* __restrict__ bcnt,
                                              const float* __restrict__ W1, ushort* __restrict__ W1T,
                                              int* __restrict__ offsets, int N, int E) {
    int b = blockIdx.x, t = threadIdx.x;
    if (b < 2) {
        bcnt[b * 256 + t] = 0;
        if (b == 0 && t == 0) offsets[N] = E;
        return;
    }
    int n = b - 2;
    W1T[n * 256 + t] = f2bf(W1[t * 128 + n]);
}

// ---------------- Pass 1: partition edges into 256-node buckets ----------------
// global record: src | ((dst&255)<<20)  (src < 2^20, bucket = blockIdx of pass 2)
__global__ __launch_bounds__(256) void k_part(const int* __restrict__ esrc, const int* __restrict__ edst, int E,
                                              int* __restrict__ bcnt, int* __restrict__ part) {
    __shared__ int sh_cnt[512];
    __shared__ int sh_base[512];
    __shared__ int sh_gbase[512];
    __shared__ int sh_scan[256];
    __shared__ int2 sh_rec[CHUNK];
    int t = threadIdx.x;
    int c0 = blockIdx.x * CHUNK;
    int cnt = min(CHUNK, E - c0);
    sh_cnt[t] = 0; sh_cnt[t + 256] = 0;
    __syncthreads();
    int srcv[16], dstv[16], lrank[16];
#pragma unroll
    for (int j = 0; j < 16; j++) {
        int li = j * 256 + t;
        if (li < cnt) {
            srcv[j] = __builtin_nontemporal_load(&esrc[c0 + li]);
            dstv[j] = __builtin_nontemporal_load(&edst[c0 + li]);
            lrank[j] = atomicAdd(&sh_cnt[dstv[j] >> BK_SHIFT], 1);
        }
    }
    __syncthreads();
    int pairsum = sh_cnt[2 * t] + sh_cnt[2 * t + 1];
    sh_scan[t] = pairsum;
    __syncthreads();
    for (int off = 1; off < 256; off <<= 1) {
        int x = 0;
        if (t >= off) x = sh_scan[t - off];
        __syncthreads();
        if (t >= off) sh_scan[t] += x;
        __syncthreads();
    }
    int excl = sh_scan[t] - pairsum;
    sh_base[2 * t] = excl;
    sh_base[2 * t + 1] = excl + sh_cnt[2 * t];
    __syncthreads();
    for (int b = t; b < 512; b += 256) {
        int c = sh_cnt[b];
        if (c > 0) sh_gbase[b] = atomicAdd(&bcnt[b], c);
    }
#pragma unroll
    for (int j = 0; j < 16; j++) {
        int li = j * 256 + t;
        if (li < cnt) {
            int b = dstv[j] >> BK_SHIFT;
            sh_rec[sh_base[b] + lrank[j]] = make_int2(srcv[j], dstv[j]);
        }
    }
    __syncthreads();
    for (int idx = t; idx < cnt; idx += 256) {
        int2 r = sh_rec[idx];
        int b = r.y >> BK_SHIFT;
        int pos = sh_gbase[b] + (idx - sh_base[b]);
        if (pos < BK_CAP)
            __builtin_nontemporal_store(r.x | ((r.y & 255) << 20),
                                        &part[(size_t)b * BK_CAP + pos]);
    }
}

// ---------------- Pass 2: per-bucket counting sort -> csr(src-only), dis, offsets ----------------
// computes its own bucket base from bcnt (k_bscan folded in)
__global__ __launch_bounds__(256) void k_bsort(const int* __restrict__ bcnt,
                                               const int* __restrict__ part,
                                               float* __restrict__ dis, int* __restrict__ offsets,
                                               int* __restrict__ csr, int N) {
    __shared__ int hist[256];
    __shared__ int run[256];
    __shared__ int sh_scan[256];
    __shared__ int sh_base;
    __shared__ int srt[BK_CAP];
    int b = blockIdx.x, t = threadIdx.x;
    // bucket base = exclusive scan of bcnt over [0, b)
    int a0 = bcnt[2 * t], a1 = bcnt[2 * t + 1];
    int pairsum = a0 + a1;
    sh_scan[t] = pairsum;
    hist[t] = 0;
    __syncthreads();
    for (int off = 1; off < 256; off <<= 1) {
        int x = 0;
        if (t >= off) x = sh_scan[t - off];
        __syncthreads();
        if (t >= off) sh_scan[t] += x;
        __syncthreads();
    }
    if (t == (b >> 1)) {
        int incl = sh_scan[t];                    // pairs 0..t inclusive
        sh_base = incl - pairsum + ((b & 1) ? a0 : 0);
    }
    __syncthreads();
    int base = sh_base;
    int cnt = min(bcnt[b], BK_CAP);
    const int* bp = &part[(size_t)b * BK_CAP];
    for (int idx = t; idx < cnt; idx += 256)
        atomicAdd(&hist[__builtin_nontemporal_load(&bp[idx]) >> 20], 1);
    __syncthreads();
    int v = hist[t];
    run[t] = v;
    __syncthreads();
    for (int off = 1; off < 256; off <<= 1) {
        int x = 0;
        if (t >= off) x = run[t - off];
        __syncthreads();
        if (t >= off) run[t] += x;
        __syncthreads();
    }
    int start = run[t] - v;
    int node = b * 256 + t;
    if (node < N) {
        dis[node] = rsqrtf((float)(v + 1));   // +1 self loop
        offsets[node] = base + start;
    }
    __syncthreads();
    run[t] = start;
    __syncthreads();
    for (int idx = t; idx < cnt; idx += 256) {
        int r = bp[idx];
        int lpos = atomicAdd(&run[r >> 20], 1);
        srt[lpos] = r & 0xFFFFF;
    }
    __syncthreads();
    for (int idx = t; idx < cnt; idx += 256)
        __builtin_nontemporal_store(srt[idx], &csr[base + idx]);
}

// ---------------- GEMM1 (MFMA bf16): h1'[r] = bf16((x@W1)[r] * dis[r]) ----------------
__global__ __launch_bounds__(256) void k_gemm1(const float* __restrict__ x,
                                               const ushort* __restrict__ W1T,
                                               const float* __restrict__ dis,
                                               ushort* __restrict__ h1, int N) {
    __shared__ ushort Al[128 * 64];
    __shared__ ushort Bl[128 * 64];
    int tid = threadIdx.x;
    int lane = tid & 63, wid = tid >> 6;
    int wr = wid >> 1, wc = wid & 1;
    int r0 = blockIdx.x * 128;
    int row16 = lane & 15, kgrp = lane >> 4;

    f32x4 acc[4][4];
#pragma unroll
    for (int i = 0; i < 4; i++)
#pragma unroll
        for (int j = 0; j < 4; j++) acc[i][j] = (f32x4){0.f, 0.f, 0.f, 0.f};

    int srow = tid >> 1, shalf = tid & 1;

    for (int k0 = 0; k0 < 256; k0 += 64) {
        {
            int gr = r0 + srow;
            float4 f[8];
            if (gr < N) {
                const float* xp = &x[(size_t)gr * 256 + k0 + shalf * 32];
#pragma unroll
                for (int j = 0; j < 8; j++) f[j] = *(const float4*)&xp[j * 4];
            } else {
#pragma unroll
                for (int j = 0; j < 8; j++) f[j] = make_float4(0.f, 0.f, 0.f, 0.f);
            }
#pragma unroll
            for (int j = 0; j < 4; j++) {
                uint4 w;
                w.x = pk2(f[2 * j].x, f[2 * j].y);
                w.y = pk2(f[2 * j].z, f[2 * j].w);
                w.z = pk2(f[2 * j + 1].x, f[2 * j + 1].y);
                w.w = pk2(f[2 * j + 1].z, f[2 * j + 1].w);
                int idx = (srow * 64 + shalf * 32 + j * 8) ^ ((srow & 7) << 3);
                *(uint4*)&Al[idx] = w;
            }
        }
        {
            const ushort* wp = &W1T[srow * 256 + k0 + shalf * 32];
#pragma unroll
            for (int j = 0; j < 4; j++) {
                uint4 w = *(const uint4*)&wp[j * 8];
                int idx = (srow * 64 + shalf * 32 + j * 8) ^ ((srow & 7) << 3);
                *(uint4*)&Bl[idx] = w;
            }
        }
        __syncthreads();
#pragma unroll
        for (int kk = 0; kk < 2; kk++) {
            bf16x8 a[4], b[4];
#pragma unroll
            for (int mi = 0; mi < 4; mi++) {
                int r = wr * 64 + mi * 16 + row16;
                a[mi] = *(const bf16x8*)&Al[(r * 64 + kk * 32 + kgrp * 8) ^ ((r & 7) << 3)];
            }
#pragma unroll
            for (int ni = 0; ni < 4; ni++) {
                int c = wc * 64 + ni * 16 + row16;
                b[ni] = *(const bf16x8*)&Bl[(c * 64 + kk * 32 + kgrp * 8) ^ ((c & 7) << 3)];
            }
#pragma unroll
            for (int mi = 0; mi < 4; mi++)
#pragma unroll
                for (int ni = 0; ni < 4; ni++)
                    acc[mi][ni] = __builtin_amdgcn_mfma_f32_16x16x32_bf16(
                        a[mi], b[ni], acc[mi][ni], 0, 0, 0);
        }
        __syncthreads();
    }
#pragma unroll
    for (int mi = 0; mi < 4; mi++) {
        int rbase = r0 + wr * 64 + mi * 16 + kgrp * 4;
        float ds[4];
#pragma unroll
        for (int r = 0; r < 4; r++) {
            int gr = rbase + r;
            ds[r] = (gr < N) ? dis[gr] : 0.f;
        }
#pragma unroll
        for (int ni = 0; ni < 4; ni++) {
            int col = wc * 64 + ni * 16 + row16;
#pragma unroll
            for (int r = 0; r < 4; r++) {
                int gr = rbase + r;
                if (gr < N)
                    __builtin_nontemporal_store(f2bf(acc[mi][ni][r] * ds[r]),
                                                &h1[(size_t)gr * 128 + col]);
            }
        }
    }
}

// ---------------- Fused agg1 + bias + ReLU + GEMM2 (pure gather-sum, depth-8) ----------------
__global__ __launch_bounds__(256) void k_agg1(const ushort* __restrict__ h1,
                                              const float* __restrict__ dis,
                                              const int* __restrict__ off,
                                              const int* __restrict__ csr,
                                              const float* __restrict__ b1,
                                              const float* __restrict__ W2,
                                              ushort* __restrict__ h2, int N) {
    __shared__ float sh[4][128];
    int wave = threadIdx.x >> 6;
    int lane = threadIdx.x & 63;
    int node = blockIdx.x * 4 + wave;
    if (node >= N) return;

    int grp = lane >> 4, c = lane & 15;
    float w2r[32];
#pragma unroll
    for (int j = 0; j < 32; j++) w2r[j] = W2[(grp * 32 + j) * 16 + c];
    float2 bl = *(const float2*)&b1[lane * 2];

    float dd = dis[node];
    const uint* hp = (const uint*)h1;
    uint a = hp[(size_t)node * 64 + lane];
    float accx = bflo(a), accy = bfhi(a);   // self loop: h1' already carries dis[node]

    int p0 = off[node], p1 = off[node + 1];
    for (int pb = p0; pb < p1; pb += 64) {
        int cnt = min(64, p1 - pb);
        int s = 0;
        if (lane < cnt) s = __builtin_nontemporal_load(&csr[pb + lane]);
        int j = 0;
        for (; j + 8 <= cnt; j += 8) {
            uint v[8];
#pragma unroll
            for (int u = 0; u < 8; u++) {
                int ss = __shfl(s, j + u);
                v[u] = hp[(size_t)ss * 64 + lane];
            }
#pragma unroll
            for (int u = 0; u < 8; u++) {
                accx += bflo(v[u]);
                accy += bfhi(v[u]);
            }
        }
        int rem = cnt - j;
        if (rem) {
            uint v[8];
#pragma unroll
            for (int u = 0; u < 8; u++) {
                int ss = __shfl(s, j + u);
                v[u] = (u < rem) ? hp[(size_t)ss * 64 + lane] : 0u;
            }
#pragma unroll
            for (int u = 0; u < 8; u++) {
                accx += bflo(v[u]);
                accy += bfhi(v[u]);
            }
        }
    }
    accx = fmaxf(accx * dd + bl.x, 0.f);
    accy = fmaxf(accy * dd + bl.y, 0.f);
    sh[wave][lane * 2]     = accx;
    sh[wave][lane * 2 + 1] = accy;
    float cs = 0.f;
#pragma unroll
    for (int j = 0; j < 32; j++) cs += sh[wave][grp * 32 + j] * w2r[j];
    cs += __shfl_xor(cs, 16);
    cs += __shfl_xor(cs, 32);
    if (lane < 16)
        __builtin_nontemporal_store(f2bf(cs * dd), &h2[(size_t)node * 16 + lane]);
}

// ---------------- Aggregation layer 2 + b2 + log_softmax (pure gather-sum, depth-8) ----------------
__global__ __launch_bounds__(256) void k_final(const ushort* __restrict__ h2,
                                               const float* __restrict__ b2,
                                               const float* __restrict__ dis,
                                               const int* __restrict__ off,
                                               const int* __restrict__ csr,
                                               float* __restrict__ out, int N) {
    int g = threadIdx.x >> 2;
    int q = threadIdx.x & 3;
    int node = blockIdx.x * 64 + g;
    if (node >= N) return;
    float dd = dis[node];
    uint2 v0 = *(const uint2*)&h2[(size_t)node * 16 + q * 4];
    float a0 = bflo(v0.x), a1 = bfhi(v0.x);   // self loop: h2' carries dis[node]
    float a2 = bflo(v0.y), a3 = bfhi(v0.y);
    int p0 = off[node], p1 = off[node + 1];
    for (int pb = p0; pb < p1; pb += 8) {
        int cnt = min(8, p1 - pb);
        int s0 = 0, s1 = 0;
        if (q < cnt) s0 = __builtin_nontemporal_load(&csr[pb + q]);
        if (q + 4 < cnt) s1 = __builtin_nontemporal_load(&csr[pb + 4 + q]);
        uint2 vv[8];
#pragma unroll
        for (int u = 0; u < 8; u++) {
            int ss = (u < 4) ? __shfl(s0, u, 4) : __shfl(s1, u - 4, 4);
            vv[u] = (u < cnt) ? *(const uint2*)&h2[(size_t)ss * 16 + q * 4]
                              : make_uint2(0u, 0u);
        }
#pragma unroll
        for (int u = 0; u < 8; u++) {
            a0 += bflo(vv[u].x); a1 += bfhi(vv[u].x);
            a2 += bflo(vv[u].y); a3 += bfhi(vv[u].y);
        }
    }
    a0 = a0 * dd + b2[q * 4 + 0];
    a1 = a1 * dd + b2[q * 4 + 1];
    a2 = a2 * dd + b2[q * 4 + 2];
    a3 = a3 * dd + b2[q * 4 + 3];
    float m = fmaxf(fmaxf(a0, a1), fmaxf(a2, a3));
    m = fmaxf(m, __shfl_xor(m, 1, 4));
    m = fmaxf(m, __shfl_xor(m, 2, 4));
    float s4 = expf(a0 - m) + expf(a1 - m) + expf(a2 - m) + expf(a3 - m);
    s4 += __shfl_xor(s4, 1, 4);
    s4 += __shfl_xor(s4, 2, 4);
    float l = m + logf(s4);
    f32x4 o = {a0 - l, a1 - l, a2 - l, a3 - l};
    *(f32x4*)&out[(size_t)node * 16 + q * 4] = o;
}

extern "C" void kernel_launch(void* const* d_in, const int* in_sizes, int n_in,
                              void* d_out, int out_size, void* d_ws, size_t ws_size,
                              hipStream_t stream) {
    const float* x    = (const float*)d_in[0];
    const int*   eidx = (const int*)d_in[1];
    const float* W1   = (const float*)d_in[2];
    const float* b1   = (const float*)d_in[3];
    const float* W2   = (const float*)d_in[4];
    const float* b2   = (const float*)d_in[5];
    float* out = (float*)d_out;

    int N = in_sizes[0] / IN_DIM;
    int E = in_sizes[1] / 2;
    const int* esrc = eidx;
    const int* edst = eidx + E;

    char* ws = (char*)d_ws;
    size_t wo = 0;
    auto alloc = [&](size_t bytes) -> void* {
        void* p = ws + wo;
        wo = (wo + bytes + 255) & ~(size_t)255;
        return p;
    };
    int NB = (N + 255) >> 8;   // 256-node buckets

    float*  dis     = (float*)alloc((size_t)N * 4);
    int*    offsets = (int*)alloc((size_t)(N + 1) * 4);
    int*    bcnt    = (int*)alloc(512 * 4);
    int*    part    = (int*)alloc((size_t)NB * BK_CAP * 4);
    int*    csr     = (int*)alloc((size_t)E * 4);
    ushort* W1T     = (ushort*)alloc((size_t)IN_DIM * H_DIM * 2);
    ushort* h1      = (ushort*)alloc((size_t)N * H_DIM * 2);
    ushort* h2      = (ushort*)alloc((size_t)N * C_DIM * 2);

    k_prep  <<<130, 256, 0, stream>>>(bcnt, W1, W1T, offsets, N, E);
    k_part  <<<(E + CHUNK - 1) / CHUNK, 256, 0, stream>>>(esrc, edst, E, bcnt, part);
    k_bsort <<<NB, 256, 0, stream>>>(bcnt, part, dis, offsets, csr, N);

    k_gemm1 <<<(N + 127) / 128, 256, 0, stream>>>(x, W1T, dis, h1, N);
    k_agg1  <<<(N + 3) / 4, 256, 0, stream>>>(h1, dis, offsets, csr, b1, W2, h2, N);
    k_final <<<(N + 63) / 64, 256, 0, stream>>>(h2, b2, dis, offsets, csr, out, N);
}

// Round 12
// 169.293 us; speedup vs baseline: 1.1436x; 1.1436x over previous
//
#include <hip/hip_runtime.h>
#include <math.h>

#define IN_DIM 256
#define H_DIM  128
#define C_DIM  16
#define BK_SHIFT 8
#define BK_CAP   6144
#define CHUNK    4096

typedef __attribute__((ext_vector_type(8))) short bf16x8;
typedef __attribute__((ext_vector_type(4))) float f32x4;

__device__ __forceinline__ ushort f2bf(float f) {
    uint u = __float_as_uint(f);
    u += 0x7fffu + ((u >> 16) & 1u);   // round to nearest even
    return (ushort)(u >> 16);
}
__device__ __forceinline__ float bflo(uint v) { return __uint_as_float(v << 16); }
__device__ __forceinline__ float bfhi(uint v) { return __uint_as_float(v & 0xffff0000u); }
__device__ __forceinline__ uint pk2(float a, float b) {
    return (uint)f2bf(a) | ((uint)f2bf(b) << 16);
}

// ---------------- fused: zero bcnt + W1 cast/transpose + offsets[N]=E ----------------
__global__ __launch_bounds__(256) void k_prep(int* __restrict__ bcnt,
                                              const float* __restrict__ W1, ushort* __restrict__ W1T,
                                              int* __restrict__ offsets, int N, int E) {
    int b = blockIdx.x, t = threadIdx.x;
    if (b < 2) {
        bcnt[b * 256 + t] = 0;
        if (b == 0 && t == 0) offsets[N] = E;
        return;
    }
    int n = b - 2;
    W1T[n * 256 + t] = f2bf(W1[t * 128 + n]);
}

// ---------------- Pass 1: partition edges into 256-node buckets ----------------
// global record: src | ((dst&255)<<20)  (src < 2^20, bucket = blockIdx of pass 2)
__global__ __launch_bounds__(256) void k_part(const int* __restrict__ esrc, const int* __restrict__ edst, int E,
                                              int* __restrict__ bcnt, int* __restrict__ part) {
    __shared__ int sh_cnt[512];
    __shared__ int sh_base[512];
    __shared__ int sh_gbase[512];
    __shared__ int sh_scan[256];
    __shared__ int2 sh_rec[CHUNK];
    int t = threadIdx.x;
    int c0 = blockIdx.x * CHUNK;
    int cnt = min(CHUNK, E - c0);
    sh_cnt[t] = 0; sh_cnt[t + 256] = 0;
    __syncthreads();
    int srcv[16], dstv[16], lrank[16];
#pragma unroll
    for (int j = 0; j < 16; j++) {
        int li = j * 256 + t;
        if (li < cnt) {
            srcv[j] = esrc[c0 + li]; dstv[j] = edst[c0 + li];
            lrank[j] = atomicAdd(&sh_cnt[dstv[j] >> BK_SHIFT], 1);
        }
    }
    __syncthreads();
    int pairsum = sh_cnt[2 * t] + sh_cnt[2 * t + 1];
    sh_scan[t] = pairsum;
    __syncthreads();
    for (int off = 1; off < 256; off <<= 1) {
        int x = 0;
        if (t >= off) x = sh_scan[t - off];
        __syncthreads();
        if (t >= off) sh_scan[t] += x;
        __syncthreads();
    }
    int excl = sh_scan[t] - pairsum;
    sh_base[2 * t] = excl;
    sh_base[2 * t + 1] = excl + sh_cnt[2 * t];
    __syncthreads();
    for (int b = t; b < 512; b += 256) {
        int c = sh_cnt[b];
        if (c > 0) sh_gbase[b] = atomicAdd(&bcnt[b], c);
    }
#pragma unroll
    for (int j = 0; j < 16; j++) {
        int li = j * 256 + t;
        if (li < cnt) {
            int b = dstv[j] >> BK_SHIFT;
            sh_rec[sh_base[b] + lrank[j]] = make_int2(srcv[j], dstv[j]);
        }
    }
    __syncthreads();
    for (int idx = t; idx < cnt; idx += 256) {
        int2 r = sh_rec[idx];
        int b = r.y >> BK_SHIFT;
        int pos = sh_gbase[b] + (idx - sh_base[b]);
        if (pos < BK_CAP)
            part[(size_t)b * BK_CAP + pos] = r.x | ((r.y & 255) << 20);
    }
}

// ---------------- Pass 2: per-bucket counting sort -> csr(src-only), dis, offsets ----------------
// computes its own bucket base from bcnt (k_bscan folded in)
__global__ __launch_bounds__(256) void k_bsort(const int* __restrict__ bcnt,
                                               const int* __restrict__ part,
                                               float* __restrict__ dis, int* __restrict__ offsets,
                                               int* __restrict__ csr, int N) {
    __shared__ int hist[256];
    __shared__ int run[256];
    __shared__ int sh_scan[256];
    __shared__ int sh_base;
    __shared__ int srt[BK_CAP];
    int b = blockIdx.x, t = threadIdx.x;
    // bucket base = exclusive scan of bcnt over [0, b)
    int a0 = bcnt[2 * t], a1 = bcnt[2 * t + 1];
    int pairsum = a0 + a1;
    sh_scan[t] = pairsum;
    hist[t] = 0;
    __syncthreads();
    for (int off = 1; off < 256; off <<= 1) {
        int x = 0;
        if (t >= off) x = sh_scan[t - off];
        __syncthreads();
        if (t >= off) sh_scan[t] += x;
        __syncthreads();
    }
    if (t == (b >> 1)) {
        int incl = sh_scan[t];                    // pairs 0..t inclusive
        sh_base = incl - pairsum + ((b & 1) ? a0 : 0);
    }
    __syncthreads();
    int base = sh_base;
    int cnt = min(bcnt[b], BK_CAP);
    const int* bp = &part[(size_t)b * BK_CAP];
    for (int idx = t; idx < cnt; idx += 256)
        atomicAdd(&hist[bp[idx] >> 20], 1);
    __syncthreads();
    int v = hist[t];
    run[t] = v;
    __syncthreads();
    for (int off = 1; off < 256; off <<= 1) {
        int x = 0;
        if (t >= off) x = run[t - off];
        __syncthreads();
        if (t >= off) run[t] += x;
        __syncthreads();
    }
    int start = run[t] - v;
    int node = b * 256 + t;
    if (node < N) {
        dis[node] = rsqrtf((float)(v + 1));   // +1 self loop
        offsets[node] = base + start;
    }
    __syncthreads();
    run[t] = start;
    __syncthreads();
    for (int idx = t; idx < cnt; idx += 256) {
        int r = bp[idx];
        int lpos = atomicAdd(&run[r >> 20], 1);
        srt[lpos] = r & 0xFFFFF;
    }
    __syncthreads();
    for (int idx = t; idx < cnt; idx += 256)
        csr[base + idx] = srt[idx];
}

// ---------------- GEMM1 (MFMA bf16): h1'[r] = bf16((x@W1)[r] * dis[r]) ----------------
__global__ __launch_bounds__(256) void k_gemm1(const float* __restrict__ x,
                                               const ushort* __restrict__ W1T,
                                               const float* __restrict__ dis,
                                               ushort* __restrict__ h1, int N) {
    __shared__ ushort Al[128 * 64];
    __shared__ ushort Bl[128 * 64];
    int tid = threadIdx.x;
    int lane = tid & 63, wid = tid >> 6;
    int wr = wid >> 1, wc = wid & 1;
    int r0 = blockIdx.x * 128;
    int row16 = lane & 15, kgrp = lane >> 4;

    f32x4 acc[4][4];
#pragma unroll
    for (int i = 0; i < 4; i++)
#pragma unroll
        for (int j = 0; j < 4; j++) acc[i][j] = (f32x4){0.f, 0.f, 0.f, 0.f};

    int srow = tid >> 1, shalf = tid & 1;

    for (int k0 = 0; k0 < 256; k0 += 64) {
        {
            int gr = r0 + srow;
            float4 f[8];
            if (gr < N) {
                const float* xp = &x[(size_t)gr * 256 + k0 + shalf * 32];
#pragma unroll
                for (int j = 0; j < 8; j++) f[j] = *(const float4*)&xp[j * 4];
            } else {
#pragma unroll
                for (int j = 0; j < 8; j++) f[j] = make_float4(0.f, 0.f, 0.f, 0.f);
            }
#pragma unroll
            for (int j = 0; j < 4; j++) {
                uint4 w;
                w.x = pk2(f[2 * j].x, f[2 * j].y);
                w.y = pk2(f[2 * j].z, f[2 * j].w);
                w.z = pk2(f[2 * j + 1].x, f[2 * j + 1].y);
                w.w = pk2(f[2 * j + 1].z, f[2 * j + 1].w);
                int idx = (srow * 64 + shalf * 32 + j * 8) ^ ((srow & 7) << 3);
                *(uint4*)&Al[idx] = w;
            }
        }
        {
            const ushort* wp = &W1T[srow * 256 + k0 + shalf * 32];
#pragma unroll
            for (int j = 0; j < 4; j++) {
                uint4 w = *(const uint4*)&wp[j * 8];
                int idx = (srow * 64 + shalf * 32 + j * 8) ^ ((srow & 7) << 3);
                *(uint4*)&Bl[idx] = w;
            }
        }
        __syncthreads();
#pragma unroll
        for (int kk = 0; kk < 2; kk++) {
            bf16x8 a[4], b[4];
#pragma unroll
            for (int mi = 0; mi < 4; mi++) {
                int r = wr * 64 + mi * 16 + row16;
                a[mi] = *(const bf16x8*)&Al[(r * 64 + kk * 32 + kgrp * 8) ^ ((r & 7) << 3)];
            }
#pragma unroll
            for (int ni = 0; ni < 4; ni++) {
                int c = wc * 64 + ni * 16 + row16;
                b[ni] = *(const bf16x8*)&Bl[(c * 64 + kk * 32 + kgrp * 8) ^ ((c & 7) << 3)];
            }
#pragma unroll
            for (int mi = 0; mi < 4; mi++)
#pragma unroll
                for (int ni = 0; ni < 4; ni++)
                    acc[mi][ni] = __builtin_amdgcn_mfma_f32_16x16x32_bf16(
                        a[mi], b[ni], acc[mi][ni], 0, 0, 0);
        }
        __syncthreads();
    }
#pragma unroll
    for (int mi = 0; mi < 4; mi++) {
        int rbase = r0 + wr * 64 + mi * 16 + kgrp * 4;
        float ds[4];
#pragma unroll
        for (int r = 0; r < 4; r++) {
            int gr = rbase + r;
            ds[r] = (gr < N) ? dis[gr] : 0.f;
        }
#pragma unroll
        for (int ni = 0; ni < 4; ni++) {
            int col = wc * 64 + ni * 16 + row16;
#pragma unroll
            for (int r = 0; r < 4; r++) {
                int gr = rbase + r;
                if (gr < N) h1[(size_t)gr * 128 + col] = f2bf(acc[mi][ni][r] * ds[r]);
            }
        }
    }
}

// ---------------- Fused agg1 + bias + ReLU + GEMM2 (pure gather-sum, depth-8) ----------------
__global__ __launch_bounds__(256) void k_agg1(const ushort* __restrict__ h1,
                                              const float* __restrict__ dis,
                                              const int* __restrict__ off,
                                              const int* __restrict__ csr,
                                              const float* __restrict__ b1,
                                              const float* __restrict__ W2,
                                              ushort* __restrict__ h2, int N) {
    __shared__ float sh[4][128];
    int wave = threadIdx.x >> 6;
    int lane = threadIdx.x & 63;
    int node = blockIdx.x * 4 + wave;
    if (node >= N) return;

    int grp = lane >> 4, c = lane & 15;
    float w2r[32];
#pragma unroll
    for (int j = 0; j < 32; j++) w2r[j] = W2[(grp * 32 + j) * 16 + c];
    float2 bl = *(const float2*)&b1[lane * 2];

    float dd = dis[node];
    const uint* hp = (const uint*)h1;
    uint a = hp[(size_t)node * 64 + lane];
    float accx = bflo(a), accy = bfhi(a);   // self loop: h1' already carries dis[node]

    int p0 = off[node], p1 = off[node + 1];
    for (int pb = p0; pb < p1; pb += 64) {
        int cnt = min(64, p1 - pb);
        int s = 0;
        if (lane < cnt) s = csr[pb + lane];
        int j = 0;
        for (; j + 8 <= cnt; j += 8) {
            uint v[8];
#pragma unroll
            for (int u = 0; u < 8; u++) {
                int ss = __shfl(s, j + u);
                v[u] = hp[(size_t)ss * 64 + lane];
            }
#pragma unroll
            for (int u = 0; u < 8; u++) {
                accx += bflo(v[u]);
                accy += bfhi(v[u]);
            }
        }
        int rem = cnt - j;
        if (rem) {
            uint v[8];
#pragma unroll
            for (int u = 0; u < 8; u++) {
                int ss = __shfl(s, j + u);
                v[u] = (u < rem) ? hp[(size_t)ss * 64 + lane] : 0u;
            }
#pragma unroll
            for (int u = 0; u < 8; u++) {
                accx += bflo(v[u]);
                accy += bfhi(v[u]);
            }
        }
    }
    accx = fmaxf(accx * dd + bl.x, 0.f);
    accy = fmaxf(accy * dd + bl.y, 0.f);
    sh[wave][lane * 2]     = accx;
    sh[wave][lane * 2 + 1] = accy;
    float cs = 0.f;
#pragma unroll
    for (int j = 0; j < 32; j++) cs += sh[wave][grp * 32 + j] * w2r[j];
    cs += __shfl_xor(cs, 16);
    cs += __shfl_xor(cs, 32);
    if (lane < 16) h2[(size_t)node * 16 + lane] = f2bf(cs * dd);  // store h2' = h2 * dis[node]
}

// ---------------- Aggregation layer 2 + b2 + log_softmax (pure gather-sum, depth-8) ----------------
__global__ __launch_bounds__(256) void k_final(const ushort* __restrict__ h2,
                                               const float* __restrict__ b2,
                                               const float* __restrict__ dis,
                                               const int* __restrict__ off,
                                               const int* __restrict__ csr,
                                               float* __restrict__ out, int N) {
    int g = threadIdx.x >> 2;
    int q = threadIdx.x & 3;
    int node = blockIdx.x * 64 + g;
    if (node >= N) return;
    float dd = dis[node];
    uint2 v0 = *(const uint2*)&h2[(size_t)node * 16 + q * 4];
    float a0 = bflo(v0.x), a1 = bfhi(v0.x);   // self loop: h2' carries dis[node]
    float a2 = bflo(v0.y), a3 = bfhi(v0.y);
    int p0 = off[node], p1 = off[node + 1];
    for (int pb = p0; pb < p1; pb += 8) {
        int cnt = min(8, p1 - pb);
        int s0 = 0, s1 = 0;
        if (q < cnt) s0 = csr[pb + q];
        if (q + 4 < cnt) s1 = csr[pb + 4 + q];
        uint2 vv[8];
#pragma unroll
        for (int u = 0; u < 8; u++) {
            int ss = (u < 4) ? __shfl(s0, u, 4) : __shfl(s1, u - 4, 4);
            vv[u] = (u < cnt) ? *(const uint2*)&h2[(size_t)ss * 16 + q * 4]
                              : make_uint2(0u, 0u);
        }
#pragma unroll
        for (int u = 0; u < 8; u++) {
            a0 += bflo(vv[u].x); a1 += bfhi(vv[u].x);
            a2 += bflo(vv[u].y); a3 += bfhi(vv[u].y);
        }
    }
    a0 = a0 * dd + b2[q * 4 + 0];
    a1 = a1 * dd + b2[q * 4 + 1];
    a2 = a2 * dd + b2[q * 4 + 2];
    a3 = a3 * dd + b2[q * 4 + 3];
    float m = fmaxf(fmaxf(a0, a1), fmaxf(a2, a3));
    m = fmaxf(m, __shfl_xor(m, 1, 4));
    m = fmaxf(m, __shfl_xor(m, 2, 4));
    float s4 = expf(a0 - m) + expf(a1 - m) + expf(a2 - m) + expf(a3 - m);
    s4 += __shfl_xor(s4, 1, 4);
    s4 += __shfl_xor(s4, 2, 4);
    float l = m + logf(s4);
    f32x4 o = {a0 - l, a1 - l, a2 - l, a3 - l};
    *(f32x4*)&out[(size_t)node * 16 + q * 4] = o;
}

extern "C" void kernel_launch(void* const* d_in, const int* in_sizes, int n_in,
                              void* d_out, int out_size, void* d_ws, size_t ws_size,
                              hipStream_t stream) {
    const float* x    = (const float*)d_in[0];
    const int*   eidx = (const int*)d_in[1];
    const float* W1   = (const float*)d_in[2];
    const float* b1   = (const float*)d_in[3];
    const float* W2   = (const float*)d_in[4];
    const float* b2   = (const float*)d_in[5];
    float* out = (float*)d_out;

    int N = in_sizes[0] / IN_DIM;
    int E = in_sizes[1] / 2;
    const int* esrc = eidx;
    const int* edst = eidx + E;

    char* ws = (char*)d_ws;
    size_t wo = 0;
    auto alloc = [&](size_t bytes) -> void* {
        void* p = ws + wo;
        wo = (wo + bytes + 255) & ~(size_t)255;
        return p;
    };
    int NB = (N + 255) >> 8;   // 256-node buckets

    float*  dis     = (float*)alloc((size_t)N * 4);
    int*    offsets = (int*)alloc((size_t)(N + 1) * 4);
    int*    bcnt    = (int*)alloc(512 * 4);
    int*    part    = (int*)alloc((size_t)NB * BK_CAP * 4);
    int*    csr     = (int*)alloc((size_t)E * 4);
    ushort* W1T     = (ushort*)alloc((size_t)IN_DIM * H_DIM * 2);
    ushort* h1      = (ushort*)alloc((size_t)N * H_DIM * 2);
    ushort* h2      = (ushort*)alloc((size_t)N * C_DIM * 2);

    k_prep  <<<130, 256, 0, stream>>>(bcnt, W1, W1T, offsets, N, E);
    k_part  <<<(E + CHUNK - 1) / CHUNK, 256, 0, stream>>>(esrc, edst, E, bcnt, part);
    k_bsort <<<NB, 256, 0, stream>>>(bcnt, part, dis, offsets, csr, N);

    k_gemm1 <<<(N + 127) / 128, 256, 0, stream>>>(x, W1T, dis, h1, N);
    k_agg1  <<<(N + 3) / 4, 256, 0, stream>>>(h1, dis, offsets, csr, b1, W2, h2, N);
    k_final <<<(N + 63) / 64, 256, 0, stream>>>(h2, b2, dis, offsets, csr, out, N);
}